// Round 18
// baseline (55.594 us; speedup 1.0000x reference)
//
#include <hip/hip_runtime.h>
#include <hip/hip_bf16.h>

#define BB    8
#define CC    128
#define TLEN  8192
#define TT    32                      // t per tile
#define TSPAN 64                      // 2 tiles per block
#define NB    (BB * (TLEN / TSPAN))   // 1024 blocks -> 3/CU resident (24 waves)

typedef __attribute__((ext_vector_type(8))) short short8;
typedef __attribute__((ext_vector_type(4))) float f32x4;

__device__ __forceinline__ short f2bf(float f) {
    union { float f; unsigned u; } v; v.f = f;
    return (short)((v.u + 0x7FFFu + ((v.u >> 16) & 1u)) >> 16);
}
__device__ __forceinline__ float bf2f(unsigned short h) {
    union { unsigned u; float f; } v; v.u = ((unsigned)h) << 16;
    return v.f;
}
// y-tile swizzle (c-octets XOR by t-hash) — verified R5..R16
__device__ __forceinline__ int swzY(int t, int c) {
    return c ^ (((t ^ (t >> 3)) & 15) << 3);
}
// u32-tile swizzle on the 32-elem t-row, keyed by c/d — verified R13/R15
__device__ __forceinline__ int sfz(int c) {
    return ((c & 3) << 3) | (((c >> 2) & 1) << 2);
}

#define VMWAIT(N) asm volatile("s_waitcnt vmcnt(" #N ")" ::: "memory")
#define LGKM0     asm volatile("s_waitcnt lgkmcnt(0)" ::: "memory")
#define SB0 __builtin_amdgcn_sched_barrier(0)

// asm-pinned vector load: UNIFORM base in SGPRs + per-thread u32 byte offset.
// Result regs stay allocated and in flight until an explicit VMWAIT.
__device__ __forceinline__ f32x4 gload(const float* base, unsigned byteoff) {
    f32x4 r;
    asm volatile("global_load_dwordx4 %0, %1, %2"
                 : "=v"(r) : "v"(byteoff), "s"(base));
    return r;
}

__global__ __launch_bounds__(512, 6)   // 6 waves/EU -> 24 waves/CU (3 blocks)
void cfm_fused(const float* __restrict__ x1, const float* __restrict__ tsm,
               const float* __restrict__ z, const float* __restrict__ W,
               const float* __restrict__ blin, const int* __restrict__ xlens,
               const int* __restrict__ plens, float* __restrict__ out)
{
    __shared__ short    ybf[TT][CC];    // y bf16, swzY, 8 KB
    __shared__ unsigned zxpk[CC * TT];  // (x<<16|z) bf16, sfz, 16 KB
    __shared__ float    red[8];

    const int bi = blockIdx.x;
    const int b  = bi & 7;
    const int tb = (bi >> 3) * TSPAN;

    const int tid  = threadIdx.x;
    const int lane = tid & 63;
    const int wid  = tid >> 6;
    const int r15  = lane & 15;
    const int q4   = lane >> 4;

    const float ts  = tsm[b];
    const int   pl  = plens[b];
    const int   xl  = xlens[b];
    const float oms = 0.999999f;        // 1 - sigma
    const float cz  = 1.0f - oms * ts;
    const float cx  = ts;
    const size_t gB = (size_t)b * CC * TLEN;

    // ---- W A-frags FIRST (cvt+pin retire all prologue vmem before staging) ----
    short8 af[4];
    {
        const int row = wid * 16 + r15;
        #pragma unroll
        for (int ks = 0; ks < 4; ++ks) {
            const float4 w0 = *reinterpret_cast<const float4*>(W + row * CC + ks * 32 + q4 * 8);
            const float4 w1 = *reinterpret_cast<const float4*>(W + row * CC + ks * 32 + q4 * 8 + 4);
            short8 a;
            a[0] = f2bf(w0.x); a[1] = f2bf(w0.y); a[2] = f2bf(w0.z); a[3] = f2bf(w0.w);
            a[4] = f2bf(w1.x); a[5] = f2bf(w1.y); a[6] = f2bf(w1.z); a[7] = f2bf(w1.w);
            af[ks] = a;
        }
    }
    f32x4 blv = *reinterpret_cast<const f32x4*>(blin + wid * 16 + q4 * 4);
    asm volatile("" :: "v"(blv));       // retire bias load (exact vmcnt counting)
    SB0;

    // ---- per-thread staging geometry: row rc, 8 consecutive t (32B) ----
    const int rc = tid >> 2;            // c/d row 0..127 (wave-local: [16w,16w+16))
    const int t8 = (tid & 3) * 8;
    const int fz = sfz(rc);
    // uniform base pointers (x1, z); per-thread part entirely in u32 voffset
    const unsigned rowoff = (unsigned)((gB + (size_t)rc * TLEN) * 4);

    // ---- pinned loads: tile 0 then tile 1 (8 instr in flight) ----
    f32x4 xa0, xb0, za0, zb0, xa1, xb1, za1, zb1;
    xa0 = gload(x1, rowoff + (tb + t8) * 4u);       xb0 = gload(x1, rowoff + (tb + t8 + 4) * 4u);
    za0 = gload(z,  rowoff + (tb + t8) * 4u);       zb0 = gload(z,  rowoff + (tb + t8 + 4) * 4u);
    xa1 = gload(x1, rowoff + (tb + TT + t8) * 4u);  xb1 = gload(x1, rowoff + (tb + TT + t8 + 4) * 4u);
    za1 = gload(z,  rowoff + (tb + TT + t8) * 4u);  zb1 = gload(z,  rowoff + (tb + TT + t8 + 4) * 4u);
    SB0;

    // ---- repack: regs -> y bf16 tile + packed zx tile (wave-local rows) ----
    #define REPACK(t0k, xa, xb, za, zb) do {                                  \
        const int idx = (rc * TT + t8) ^ fz;                                  \
        _Pragma("unroll")                                                     \
        for (int j = 0; j < 4; ++j) {                                         \
            const int ta = t8 + j, tb2 = t8 + 4 + j;                          \
            const float y0 = ((t0k) + ta  < pl) ? 0.0f : cz * za[j] + cx * xa[j]; \
            const float y1 = ((t0k) + tb2 < pl) ? 0.0f : cz * zb[j] + cx * xb[j]; \
            ybf[ta][swzY(ta, rc)]   = f2bf(y0);                               \
            ybf[tb2][swzY(tb2, rc)] = f2bf(y1);                               \
            zxpk[idx + j]       = ((unsigned)(unsigned short)f2bf(xa[j]) << 16) \
                                | (unsigned)(unsigned short)f2bf(za[j]);      \
            zxpk[(idx ^ 4) + j] = ((unsigned)(unsigned short)f2bf(xb[j]) << 16) \
                                | (unsigned)(unsigned short)f2bf(zb[j]);      \
        }                                                                     \
    } while (0)

    // ---- MFMA + epilogue (8 stores/thread) ----
    float lsum = 0.0f;
    #define COMPUTE(t0k) do {                                                 \
        f32x4 acc[2];                                                         \
        acc[0] = (f32x4){0,0,0,0}; acc[1] = (f32x4){0,0,0,0};                 \
        _Pragma("unroll")                                                     \
        for (int ks = 0; ks < 4; ++ks) {                                      \
            _Pragma("unroll")                                                 \
            for (int tt = 0; tt < 2; ++tt) {                                  \
                const int tr = tt * 16 + r15;                                 \
                const short8 ya = *reinterpret_cast<const short8*>(           \
                    &ybf[tr][swzY(tr, ks * 32 + q4 * 8)]);                    \
                acc[tt] = __builtin_amdgcn_mfma_f32_16x16x32_bf16(af[ks], ya, acc[tt], 0, 0, 0); \
            }                                                                 \
        }                                                                     \
        _Pragma("unroll")                                                     \
        for (int rr = 0; rr < 4; ++rr) {                                      \
            const int d = wid * 16 + q4 * 4 + rr;                             \
            float* orow = out + 1 + (size_t)(b * CC + d) * TLEN + (t0k);      \
            const int fd = sfz(d);                                            \
            _Pragma("unroll")                                                 \
            for (int tt = 0; tt < 2; ++tt) {                                  \
                const int tl = tt * 16 + r15;                                 \
                const unsigned p = zxpk[(d * TT + tl) ^ fd];                  \
                const float zv = bf2f((unsigned short)(p & 0xFFFFu));         \
                const float xv = bf2f((unsigned short)(p >> 16));             \
                const float o2 = acc[tt][rr] + blv[rr] + oms * zv;            \
                orow[tl] = o2;                                                \
                const int tg = (t0k) + tl;                                    \
                if ((tg >= pl) & (tg < xl)) { const float df = o2 - xv; lsum += df * df; } \
            }                                                                 \
        }                                                                     \
    } while (0)

    // ================= 2-tile pipeline =================
    // tile 0: S0 landed (S1 = 4 newer still in flight)
    VMWAIT(4); SB0;
    REPACK(tb, xa0, xb0, za0, zb0);
    LGKM0; __builtin_amdgcn_s_barrier();
    COMPUTE(tb);
    __builtin_amdgcn_s_barrier();       // all waves done reading ybf/zxpk

    // tile 1: S1 landed (stores0 = 8 newer may remain)
    VMWAIT(8); SB0;
    REPACK(tb + TT, xa1, xb1, za1, zb1);
    LGKM0; __builtin_amdgcn_s_barrier();
    COMPUTE(tb + TT);

    // ---- loss: wave reduce -> block reduce -> one atomicAdd ----
    #pragma unroll
    for (int off = 32; off >= 1; off >>= 1) lsum += __shfl_down(lsum, off);
    if (lane == 0) red[wid] = lsum;
    __syncthreads();
    if (tid == 0) {
        float s = 0.0f;
        #pragma unroll
        for (int w = 0; w < 8; ++w) s += red[w];
        atomicAdd(out, s / (1024.0f * (float)(xl - pl)));   // 1/(B*C*(xl-pl))
    }
}

extern "C" void kernel_launch(void* const* d_in, const int* in_sizes, int n_in,
                              void* d_out, int out_size, void* d_ws, size_t ws_size,
                              hipStream_t stream) {
    const float* x1    = (const float*)d_in[0];
    // d_in[1] = mu (unused), d_in[2] = style (unused)
    const float* tsm   = (const float*)d_in[3];
    const float* z     = (const float*)d_in[4];
    const float* W     = (const float*)d_in[5];
    const float* blin  = (const float*)d_in[6];
    const int*   xlens = (const int*)d_in[7];
    const int*   plens = (const int*)d_in[8];
    float* out = (float*)d_out;

    hipMemsetAsync(out, 0, sizeof(float), stream);   // zero the loss slot
    cfm_fused<<<NB, 512, 0, stream>>>(x1, tsm, z, W, blin, xlens, plens, out);
}

// Round 19
// 30.270 us; speedup vs baseline: 1.8366x; 1.8366x over previous
//
#include <hip/hip_runtime.h>
#include <hip/hip_bf16.h>

#define BB    8
#define CC    128
#define TLEN  8192
#define TT    32                      // t per tile
#define NT    4                       // tiles per block
#define TSPAN 128
#define NB    (BB * (TLEN / TSPAN))   // 512 blocks = 2/CU

typedef __attribute__((ext_vector_type(8))) short short8;
typedef __attribute__((ext_vector_type(4))) float f32x4;

__device__ __forceinline__ short f2bf(float f) {
    union { float f; unsigned u; } v; v.f = f;
    return (short)((v.u + 0x7FFFu + ((v.u >> 16) & 1u)) >> 16);
}
__device__ __forceinline__ float bf2f(unsigned short h) {
    union { unsigned u; float f; } v; v.u = ((unsigned)h) << 16;
    return v.f;
}
// y-tile swizzle (c-octets XOR by t-hash) — verified R5..R18
__device__ __forceinline__ int swzY(int t, int c) {
    return c ^ (((t ^ (t >> 3)) & 15) << 3);
}
// u32-tile swizzle on the 32-elem t-row, keyed by c/d — verified R13..R18
__device__ __forceinline__ int sfz(int c) {
    return ((c & 3) << 3) | (((c >> 2) & 1) << 2);
}

#define VMWAIT(N) asm volatile("s_waitcnt vmcnt(" #N ")" ::: "memory")
#define LGKM0     asm volatile("s_waitcnt lgkmcnt(0)" ::: "memory")
#define SB0 __builtin_amdgcn_sched_barrier(0)

// asm-pinned vector load: UNIFORM base (SGPR) + per-thread u32 byte offset.
__device__ __forceinline__ f32x4 gload(const float* base, unsigned byteoff) {
    f32x4 r;
    asm volatile("global_load_dwordx4 %0, %1, %2"
                 : "=v"(r) : "v"(byteoff), "s"(base));
    return r;
}

__global__ __launch_bounds__(512, 4)   // 2 blocks/CU, VGPR cap 128
void cfm_fused(const float* __restrict__ x1, const float* __restrict__ tsm,
               const float* __restrict__ z, const float* __restrict__ W,
               const float* __restrict__ blin, const int* __restrict__ xlens,
               const int* __restrict__ plens, float* __restrict__ out)
{
    __shared__ short    ybf[TT][CC];        // y bf16, swzY, 8 KB (cross-wave)
    __shared__ unsigned zxpk[CC * TT];      // (x<<16|z) bf16, sfz, 16 KB (wave-local)
    __shared__ short    o2st[CC * NT * 34]; // o2 bf16 [d][tile][34-pad], 34 KB (wave-local)
    __shared__ float    red[8];

    const int bi = blockIdx.x;
    const int b  = bi & 7;
    const int tb = (bi >> 3) * TSPAN;

    const int tid  = threadIdx.x;
    const int lane = tid & 63;
    const int wid  = tid >> 6;
    const int r15  = lane & 15;
    const int q4   = lane >> 4;

    const float ts  = tsm[b];
    const int   pl  = plens[b];
    const int   xl  = xlens[b];
    const float oms = 0.999999f;        // 1 - sigma
    const float cz  = 1.0f - oms * ts;
    const float cx  = ts;
    const size_t gB = (size_t)b * CC * TLEN;

    // ---- W A-frags FIRST (cvt retires them before the vmcnt ladder starts) ----
    short8 af[4];
    {
        const int row = wid * 16 + r15;
        #pragma unroll
        for (int ks = 0; ks < 4; ++ks) {
            const float4 w0 = *reinterpret_cast<const float4*>(W + row * CC + ks * 32 + q4 * 8);
            const float4 w1 = *reinterpret_cast<const float4*>(W + row * CC + ks * 32 + q4 * 8 + 4);
            short8 a;
            a[0] = f2bf(w0.x); a[1] = f2bf(w0.y); a[2] = f2bf(w0.z); a[3] = f2bf(w0.w);
            a[4] = f2bf(w1.x); a[5] = f2bf(w1.y); a[6] = f2bf(w1.z); a[7] = f2bf(w1.w);
            af[ks] = a;
        }
    }
    f32x4 blv = *reinterpret_cast<const f32x4*>(blin + wid * 16 + q4 * 4);
    asm volatile("" :: "v"(blv));       // retire bias load (exact vmcnt counting)
    SB0;

    // ---- per-thread load geometry: row rc (wave-local), 8 t per tile ----
    const int rc = tid >> 2;            // c/d row; wave w owns [16w, 16w+16)
    const int t8 = (tid & 3) * 8;
    const int fz = sfz(rc);
    const unsigned rowoff = (unsigned)((gB + (size_t)rc * TLEN) * 4);

    #define XLOAD(xa, xb, za, zb, t0k) do {                                   \
        xa = gload(x1, rowoff + ((t0k) + t8) * 4u);                           \
        xb = gload(x1, rowoff + ((t0k) + t8 + 4) * 4u);                       \
        za = gload(z,  rowoff + ((t0k) + t8) * 4u);                           \
        zb = gload(z,  rowoff + ((t0k) + t8 + 4) * 4u);                       \
    } while (0)

    // ---- repack: regs -> y bf16 tile + packed zx tile (verified R18) ----
    #define REPACK(t0k, xa, xb, za, zb) do {                                  \
        const int idx = (rc * TT + t8) ^ fz;                                  \
        _Pragma("unroll")                                                     \
        for (int j = 0; j < 4; ++j) {                                         \
            const int ta = t8 + j, tb2 = t8 + 4 + j;                          \
            const float y0 = ((t0k) + ta  < pl) ? 0.0f : cz * za[j] + cx * xa[j]; \
            const float y1 = ((t0k) + tb2 < pl) ? 0.0f : cz * zb[j] + cx * xb[j]; \
            ybf[ta][swzY(ta, rc)]   = f2bf(y0);                               \
            ybf[tb2][swzY(tb2, rc)] = f2bf(y1);                               \
            zxpk[idx + j]       = ((unsigned)(unsigned short)f2bf(xa[j]) << 16) \
                                | (unsigned)(unsigned short)f2bf(za[j]);      \
            zxpk[(idx ^ 4) + j] = ((unsigned)(unsigned short)f2bf(xb[j]) << 16) \
                                | (unsigned)(unsigned short)f2bf(zb[j]);      \
        }                                                                     \
    } while (0)

    // ---- MFMA + epilogue: NO global stores — o2 -> LDS (wave-local rows) ----
    float lsum = 0.0f;
    #define COMPUTE(k, t0k) do {                                              \
        f32x4 acc[2];                                                         \
        acc[0] = (f32x4){0,0,0,0}; acc[1] = (f32x4){0,0,0,0};                 \
        _Pragma("unroll")                                                     \
        for (int ks = 0; ks < 4; ++ks) {                                      \
            _Pragma("unroll")                                                 \
            for (int tt = 0; tt < 2; ++tt) {                                  \
                const int tr = tt * 16 + r15;                                 \
                const short8 ya = *reinterpret_cast<const short8*>(           \
                    &ybf[tr][swzY(tr, ks * 32 + q4 * 8)]);                    \
                acc[tt] = __builtin_amdgcn_mfma_f32_16x16x32_bf16(af[ks], ya, acc[tt], 0, 0, 0); \
            }                                                                 \
        }                                                                     \
        _Pragma("unroll")                                                     \
        for (int rr = 0; rr < 4; ++rr) {                                      \
            const int d = wid * 16 + q4 * 4 + rr;                             \
            const int fd = sfz(d);                                            \
            _Pragma("unroll")                                                 \
            for (int tt = 0; tt < 2; ++tt) {                                  \
                const int tl = tt * 16 + r15;                                 \
                const unsigned p = zxpk[(d * TT + tl) ^ fd];                  \
                const float zv = bf2f((unsigned short)(p & 0xFFFFu));         \
                const float xv = bf2f((unsigned short)(p >> 16));             \
                const float o2 = acc[tt][rr] + blv[rr] + oms * zv;            \
                o2st[(d * NT + (k)) * 34 + tl] = f2bf(o2);                    \
                const int tg = (t0k) + tl;                                    \
                if ((tg >= pl) & (tg < xl)) { const float df = o2 - xv; lsum += df * df; } \
            }                                                                 \
        }                                                                     \
    } while (0)

    // ================= 4-tile load pipeline (no stores in flight) =================
    f32x4 xa0, xb0, za0, zb0, xa1, xb1, za1, zb1;
    XLOAD(xa0, xb0, za0, zb0, tb);          SB0;   // 4 outstanding
    XLOAD(xa1, xb1, za1, zb1, tb + TT);     SB0;   // 8

    // tile 0
    VMWAIT(4); SB0;
    REPACK(tb, xa0, xb0, za0, zb0);
    XLOAD(xa0, xb0, za0, zb0, tb + 2 * TT); SB0;   // refill set 0 -> 8 out
    LGKM0; __builtin_amdgcn_s_barrier();
    COMPUTE(0, tb);
    __builtin_amdgcn_s_barrier();

    // tile 1
    VMWAIT(4); SB0;
    REPACK(tb + TT, xa1, xb1, za1, zb1);
    XLOAD(xa1, xb1, za1, zb1, tb + 3 * TT); SB0;   // refill set 1 -> 8 out
    LGKM0; __builtin_amdgcn_s_barrier();
    COMPUTE(1, tb + TT);
    __builtin_amdgcn_s_barrier();

    // tile 2
    VMWAIT(4); SB0;
    REPACK(tb + 2 * TT, xa0, xb0, za0, zb0);
    LGKM0; __builtin_amdgcn_s_barrier();
    COMPUTE(2, tb + 2 * TT);
    __builtin_amdgcn_s_barrier();

    // tile 3
    VMWAIT(0); SB0;                                 // all loads retired
    REPACK(tb + 3 * TT, xa1, xb1, za1, zb1);
    LGKM0; __builtin_amdgcn_s_barrier();
    COMPUTE(3, tb + 3 * TT);

    // ---- monolithic store burst: 64 lanes = 64 consecutive t per instr ----
    // o2st rows are wave-local (d in [16w,16w+16)); compiler handles lds waits.
    #pragma unroll
    for (int i = 0; i < 32; ++i) {
        const int d = wid * 16 + (i >> 1);
        const int t = (i & 1) * 64 + lane;
        out[1 + (size_t)(b * CC + d) * TLEN + tb + t] =
            bf2f((unsigned short)o2st[(d * NT + (t >> 5)) * 34 + (t & 31)]);
    }

    // ---- loss: wave reduce -> block reduce -> one atomicAdd ----
    #pragma unroll
    for (int off = 32; off >= 1; off >>= 1) lsum += __shfl_down(lsum, off);
    if (lane == 0) red[wid] = lsum;
    __syncthreads();
    if (tid == 0) {
        float s = 0.0f;
        #pragma unroll
        for (int w = 0; w < 8; ++w) s += red[w];
        atomicAdd(out, s / (1024.0f * (float)(xl - pl)));   // 1/(B*C*(xl-pl))
    }
}

extern "C" void kernel_launch(void* const* d_in, const int* in_sizes, int n_in,
                              void* d_out, int out_size, void* d_ws, size_t ws_size,
                              hipStream_t stream) {
    const float* x1    = (const float*)d_in[0];
    // d_in[1] = mu (unused), d_in[2] = style (unused)
    const float* tsm   = (const float*)d_in[3];
    const float* z     = (const float*)d_in[4];
    const float* W     = (const float*)d_in[5];
    const float* blin  = (const float*)d_in[6];
    const int*   xlens = (const int*)d_in[7];
    const int*   plens = (const int*)d_in[8];
    float* out = (float*)d_out;

    hipMemsetAsync(out, 0, sizeof(float), stream);   // zero the loss slot
    cfm_fused<<<NB, 512, 0, stream>>>(x1, tsm, z, W, blin, xlens, plens, out);
}